// Round 1
// baseline (511.595 us; speedup 1.0000x reference)
//
#include <hip/hip_runtime.h>

typedef float v4f __attribute__((ext_vector_type(4)));
typedef short v8s __attribute__((ext_vector_type(8)));

// round-to-nearest-even fp32 -> bf16
__device__ __forceinline__ unsigned short f2bf_rn(float f) {
  unsigned u = __float_as_uint(f);
  return (unsigned short)((u + 0x7fffu + ((u >> 16) & 1u)) >> 16);
}

// tanh-approx gelu (JAX default) scaled by 1/PHI_C, PHI_C = sqrt(E[gelu(z)^2]) = 0.6519598
__device__ __forceinline__ float gelu_phi(float x) {
  float t = tanhf(0.7978845608f * (x + 0.044715f * x * x * x));
  return 0.5f * x * (1.0f + t) * 1.5338375f;
}

// ---------------- MLP + input prep ----------------
__global__ __launch_bounds__(256) void k_mlp1(const float* __restrict__ emb, const float* __restrict__ W0,
                                              const float* __restrict__ x1, float* __restrict__ act1,
                                              unsigned short* __restrict__ s1c, unsigned short* __restrict__ v1c)
{
  const int blk = blockIdx.x, tid = threadIdx.x;
  if (blk < 128) {
    float s = 0.f;
#pragma unroll 8
    for (int x = 0; x < 64; ++x) s += emb[blk * 64 + x] * W0[x * 256 + tid];
    act1[blk * 256 + tid] = gelu_phi(s * 0.125f);
  } else {
    // compact bf16 copies of s1 (128x64) and v1 (3x128x64)
    for (int i = (blk - 128) * 256 + tid; i < 32768; i += 2048) {
      if (i < 8192) {
        s1c[i] = f2bf_rn(x1[(i >> 6) * 256 + (i & 63)]);
      } else {
        const int t = i - 8192, g = t >> 13, r = t & 8191;
        v1c[t] = f2bf_rn(x1[(r >> 6) * 256 + 64 + (r & 63) * 3 + g]);
      }
    }
  }
}

__global__ __launch_bounds__(256) void k_mlp2(const float* __restrict__ act1, const float* __restrict__ W1,
                                              float* __restrict__ act2)
{
  const int b = blockIdx.x, j = threadIdx.x;
  float s = 0.f;
#pragma unroll 16
  for (int x = 0; x < 256; ++x) s += act1[b * 256 + x] * W1[x * 256 + j];
  act2[b * 256 + j] = gelu_phi(s * 0.0625f);
}

__global__ __launch_bounds__(256) void k_mlp3(const float* __restrict__ act2, const float* __restrict__ W2,
                                              float* __restrict__ hsT)
{
  const int o = blockIdx.x * 256 + threadIdx.x;
  const int b = o >> 6, e = o & 63;
  float s = 0.f;
#pragma unroll 16
  for (int x = 0; x < 256; ++x) s += act2[b * 256 + x] * W2[x * 64 + e];
  hsT[e * 128 + b] = gelu_phi(s * 0.0625f) * 0.125f;  // hs transposed [x][b]
}

// ---------------- main GEMM: R = (hs (x) f) @ Pmat ----------------
// Pmat is the natural row-major 4096x4096 view of P[x,u,v,w]: K=(x*64+u), N=(v*64+w).
// A[b,k] = hs[b,x]*f[b,u] built in registers. B staged via LDS (fp32->bf16, transposed to k-contig).
template<int NG>
__global__ __launch_bounds__(256) void gemm_k(
    const float* __restrict__ Pa, const float* __restrict__ Pb, const float* __restrict__ Pc,
    const unsigned short* __restrict__ fc,  // [NG*128][64] bf16
    const float* __restrict__ hsT,          // [64][128] fp32
    float* __restrict__ R, int kshift, int row0, int rowstep)
{
  __shared__ __align__(16) unsigned short ldsB[64 * 40];  // [n 0..63][k 0..31], KPAD=40 bf16
  const int tid = threadIdx.x;
  const int ks = blockIdx.x & ((1 << kshift) - 1);
  const int t2 = blockIdx.x >> kshift;
  const int nt = t2 & 63;
  const int slice = t2 >> 6;
  const float* __restrict__ P = (slice == 0) ? Pa : ((slice == 1) ? Pb : Pc);
  const int rowbase = row0 + slice * rowstep;
  const int n0 = nt * 64;
  const int lane = tid & 63, wav = tid >> 6;
  const int l16 = lane & 15, quad = lane >> 4;

  // preload f fragments: [group][mtile][u-half], 8 bf16 each (A-frag k pattern: u = h*32 + quad*8 + j)
  v8s ff[NG][2][2];
#pragma unroll
  for (int g = 0; g < NG; ++g)
#pragma unroll
    for (int mt = 0; mt < 2; ++mt)
#pragma unroll
      for (int h = 0; h < 2; ++h)
        ff[g][mt][h] = *(const v8s*)(fc + (size_t)((g * 128 + wav * 32 + mt * 16 + l16) * 64 + h * 32 + quad * 8));

  v4f acc[NG][2][4];
#pragma unroll
  for (int g = 0; g < NG; ++g)
#pragma unroll
    for (int mt = 0; mt < 2; ++mt)
#pragma unroll
      for (int nf = 0; nf < 4; ++nf) acc[g][mt][nf] = (v4f){0.f, 0.f, 0.f, 0.f};

  const int ksteps = 128 >> kshift;
  const int kbase = ks * (4096 >> kshift);
  const int tq = tid & 15, kp = tid >> 4;

#pragma unroll 2
  for (int kk = 0; kk < ksteps; ++kk) {
    const int k0 = kbase + kk * 32;
    // stage P[k0..k0+31][n0..n0+63]: each thread 2 rows x 4 cols, coalesced float4 rows
    const float* src = P + (size_t)(k0 + 2 * kp) * 4096 + n0 + 4 * tq;
    const float4 r0 = *(const float4*)src;
    const float4 r1 = *(const float4*)(src + 4096);
    __syncthreads();  // previous iteration's LDS reads done
    {
      const int nb = 4 * tq;
      *(unsigned*)&ldsB[(nb + 0) * 40 + 2 * kp] = (unsigned)f2bf_rn(r0.x) | ((unsigned)f2bf_rn(r1.x) << 16);
      *(unsigned*)&ldsB[(nb + 1) * 40 + 2 * kp] = (unsigned)f2bf_rn(r0.y) | ((unsigned)f2bf_rn(r1.y) << 16);
      *(unsigned*)&ldsB[(nb + 2) * 40 + 2 * kp] = (unsigned)f2bf_rn(r0.z) | ((unsigned)f2bf_rn(r1.z) << 16);
      *(unsigned*)&ldsB[(nb + 3) * 40 + 2 * kp] = (unsigned)f2bf_rn(r0.w) | ((unsigned)f2bf_rn(r1.w) << 16);
    }
    __syncthreads();
    const int x = k0 >> 6;
    const int hh = kk & 1;  // kbase/32 is even for nsplit in {1,2}
    const float hsv0 = hsT[x * 128 + wav * 32 + l16];
    const float hsv1 = hsT[x * 128 + wav * 32 + 16 + l16];
    v8s bfr[4];
#pragma unroll
    for (int nf = 0; nf < 4; ++nf)
      bfr[nf] = *(const v8s*)&ldsB[(nf * 16 + l16) * 40 + quad * 8];
#pragma unroll
    for (int g = 0; g < NG; ++g) {
#pragma unroll
      for (int mt = 0; mt < 2; ++mt) {
        const float hsv = mt ? hsv1 : hsv0;
        const v8s fsel = hh ? ff[g][mt][1] : ff[g][mt][0];
        v8s af;
#pragma unroll
        for (int j = 0; j < 8; ++j) {
          const float fv = __uint_as_float(((unsigned)(unsigned short)fsel[j]) << 16);
          af[j] = (short)(__float_as_uint(hsv * fv) >> 16);  // truncating bf16 (noise ~2^-9, unbiased in sum)
        }
#pragma unroll
        for (int nf = 0; nf < 4; ++nf)
          acc[g][mt][nf] = __builtin_amdgcn_mfma_f32_16x16x32_bf16(af, bfr[nf], acc[g][mt][nf], 0, 0, 0);
      }
    }
  }

  // epilogue: C/D layout col=lane&15, row=quad*4+reg
  const size_t spoff = (size_t)ks * 1408 * 4096;
#pragma unroll
  for (int g = 0; g < NG; ++g)
#pragma unroll
    for (int mt = 0; mt < 2; ++mt)
#pragma unroll
      for (int nf = 0; nf < 4; ++nf)
#pragma unroll
        for (int r = 0; r < 4; ++r) {
          const int row = rowbase + g * 128 + wav * 32 + mt * 16 + quad * 4 + r;
          const int col = n0 + nf * 16 + l16;
          R[spoff + (size_t)row * 4096 + col] = acc[g][mt][nf][r];
        }
}

// ---------------- final v-contraction + output assembly ----------------
__global__ __launch_bounds__(512) void reduce_k(const float* __restrict__ R, const float* __restrict__ x2,
                                                float* __restrict__ out, int nsplit)
{
  __shared__ float x2row[256];
  __shared__ float red[17][16][32];
  const int b = blockIdx.x >> 1, wh = blockIdx.x & 1;
  const int tid = threadIdx.x;
  const int wl = tid & 31, vq = tid >> 5;  // vq 0..15, 4 v each
  if (tid < 256) x2row[tid] = x2[b * 256 + tid];
  __syncthreads();
  const int w = wh * 32 + wl;
  float a0 = 0.f, a3 = 0.f;
  float a1[3] = {0.f, 0.f, 0.f}, a2[3] = {0.f, 0.f, 0.f};
  float s4[9] = {0.f, 0.f, 0.f, 0.f, 0.f, 0.f, 0.f, 0.f, 0.f};
  for (int sp = 0; sp < nsplit; ++sp) {
    const float* Rb = R + (size_t)sp * 1408 * 4096;
#pragma unroll
    for (int vv = 0; vv < 4; ++vv) {
      const int v = vq * 4 + vv;
      const float s2v = x2row[v];
      const float v2j0 = x2row[64 + v * 3 + 0];
      const float v2j1 = x2row[64 + v * 3 + 1];
      const float v2j2 = x2row[64 + v * 3 + 2];
      const size_t co = (size_t)v * 64 + w;
      const float r0v = Rb[(size_t)b * 4096 + co];
      const float r1v = Rb[(size_t)(128 + b) * 4096 + co];
      a0 += s2v * r0v;
      a1[0] += v2j0 * r1v; a1[1] += v2j1 * r1v; a1[2] += v2j2 * r1v;
#pragma unroll
      for (int i = 0; i < 3; ++i) {
        const float vji = (i == 0) ? v2j0 : ((i == 1) ? v2j1 : v2j2);
        const float r2v = Rb[(size_t)(256 + i * 128 + b) * 4096 + co];
        const float r3v = Rb[(size_t)(640 + i * 128 + b) * 4096 + co];
        const float r4v = Rb[(size_t)(1024 + i * 128 + b) * 4096 + co];
        a2[i] += s2v * r2v;
        a3 += vji * r3v;
        s4[i * 3 + 0] += v2j0 * r4v; s4[i * 3 + 1] += v2j1 * r4v; s4[i * 3 + 2] += v2j2 * r4v;
      }
    }
  }
  red[0][vq][wl] = a0; red[1][vq][wl] = a3;
  red[2][vq][wl] = a1[0]; red[3][vq][wl] = a1[1]; red[4][vq][wl] = a1[2];
  red[5][vq][wl] = a2[0]; red[6][vq][wl] = a2[1]; red[7][vq][wl] = a2[2];
#pragma unroll
  for (int c = 0; c < 9; ++c) red[8 + c][vq][wl] = s4[c];
  __syncthreads();
  if (tid < 32) {
    float t[17];
#pragma unroll
    for (int c = 0; c < 17; ++c) {
      float s = 0.f;
#pragma unroll
      for (int q = 0; q < 16; ++q) s += red[c][q][tid];
      t[c] = s;
    }
    const float A01 = 0.011048543f;            // 1/sqrt(2*64*64)
    const float sc = 0.015625f * 0.70710678f;  // ALPHA_2 * INV_SQ2
    const int wg = wh * 32 + tid;
    out[b * 448 + wg] = A01 * (t[0] + 0.57735027f * t[1]);
    out[b * 448 + 64 + wg * 3 + 0] = A01 * (t[2] + t[5]);
    out[b * 448 + 64 + wg * 3 + 1] = A01 * (t[3] + t[6]);
    out[b * 448 + 64 + wg * 3 + 2] = A01 * (t[4] + t[7]);
    out[b * 448 + 256 + wg * 3 + 0] = sc * (t[8 + 5] - t[8 + 7]);  // eps: s4[1][2]-s4[2][1]
    out[b * 448 + 256 + wg * 3 + 1] = sc * (t[8 + 6] - t[8 + 2]);  // s4[2][0]-s4[0][2]
    out[b * 448 + 256 + wg * 3 + 2] = sc * (t[8 + 1] - t[8 + 3]);  // s4[0][1]-s4[1][0]
  }
}

extern "C" void kernel_launch(void* const* d_in, const int* in_sizes, int n_in,
                              void* d_out, int out_size, void* d_ws, size_t ws_size,
                              hipStream_t stream)
{
  const float* emb = (const float*)d_in[0];
  const float* x1  = (const float*)d_in[1];
  const float* x2  = (const float*)d_in[2];
  const float* W0  = (const float*)d_in[3];
  const float* W1  = (const float*)d_in[4];
  const float* W2  = (const float*)d_in[5];
  const float* P0  = (const float*)d_in[6];
  const float* P1  = (const float*)d_in[7];
  const float* P2  = (const float*)d_in[8];
  const float* P3  = (const float*)d_in[9];
  const float* P4  = (const float*)d_in[10];
  float* out = (float*)d_out;
  char* ws = (char*)d_ws;

  float* hsT  = (float*)ws;                       // 8192 f32
  float* act1 = (float*)(ws + 32768);             // 32768 f32
  float* act2 = (float*)(ws + 163840);            // 32768 f32
  unsigned short* s1c = (unsigned short*)(ws + 294912);  // 8192 bf16
  unsigned short* v1c = (unsigned short*)(ws + 311296);  // 24576 bf16
  float* R = (float*)(ws + 393216);               // nsplit * 1408 * 4096 f32

  const size_t rbytes = (size_t)1408 * 4096 * 4;
  const int nsplit = (ws_size >= (size_t)393216 + 2 * rbytes) ? 2 : 1;
  const int kshift = nsplit - 1;

  k_mlp1<<<136, 256, 0, stream>>>(emb, W0, x1, act1, s1c, v1c);
  k_mlp2<<<128, 256, 0, stream>>>(act1, W1, act2);
  k_mlp3<<<32, 256, 0, stream>>>(act2, W2, hsT);
  gemm_k<1><<<2 * 64 * nsplit, 256, 0, stream>>>(P0, P1, nullptr, s1c, hsT, R, kshift, 0, 128);
  gemm_k<3><<<3 * 64 * nsplit, 256, 0, stream>>>(P2, P3, P4, v1c, hsT, R, kshift, 256, 384);
  reduce_k<<<256, 512, 0, stream>>>(R, x2, out, nsplit);
}